// Round 1
// baseline (506.176 us; speedup 1.0000x reference)
//
#include <hip/hip_runtime.h>
#include <math.h>

namespace {
constexpr int B_ = 8, L_ = 512, D_ = 512, NF = 11;
constexpr long PLANE = (long)L_ * D_;        // 262144 elements (also L*L)
constexpr long OUT_ELEMS = (long)B_ * PLANE; // 2097152
constexpr float NEGV = -1.0e9f;
constexpr float INV_TEMP = 0.044194173824159216f; // 1/sqrt(512)
}

// C = A * B^T (BT=true, B is [N,K]) or C = A * B (BT=false, B is [K,N])
// A [M,K] row-major, C [M,N] row-major. M,N,K multiples of 64/16. Batched via blockIdx.z.
template<bool BT>
__global__ __launch_bounds__(256) void gemm64(const float* __restrict__ A, const float* __restrict__ Bm,
                                              float* __restrict__ C, int M, int N, int K,
                                              long sA, long sB, long sC)
{
    __shared__ float As[16][68]; // [k][m], +4 pad keeps float4 alignment
    __shared__ float Bs[16][68]; // [k][n]
    const int bz = blockIdx.z;
    A += (long)bz * sA; Bm += (long)bz * sB; C += (long)bz * sC;
    const int m0 = blockIdx.y * 64, n0 = blockIdx.x * 64;
    const int tid = threadIdx.x;
    const int tx = tid & 15, ty = tid >> 4;
    const int arow = tid >> 2, ac4 = (tid & 3) * 4;
    float c[4][4] = {};
    for (int k0 = 0; k0 < K; k0 += 16) {
        float4 av = *(const float4*)(A + (long)(m0 + arow) * K + k0 + ac4);
        float4 bv;
        if (BT) bv = *(const float4*)(Bm + (long)(n0 + arow) * K + k0 + ac4);
        else    bv = *(const float4*)(Bm + (long)(k0 + (tid >> 4)) * N + n0 + (tid & 15) * 4);
        As[ac4 + 0][arow] = av.x; As[ac4 + 1][arow] = av.y;
        As[ac4 + 2][arow] = av.z; As[ac4 + 3][arow] = av.w;
        if (BT) {
            Bs[ac4 + 0][arow] = bv.x; Bs[ac4 + 1][arow] = bv.y;
            Bs[ac4 + 2][arow] = bv.z; Bs[ac4 + 3][arow] = bv.w;
        } else {
            *(float4*)&Bs[tid >> 4][(tid & 15) * 4] = bv;
        }
        __syncthreads();
        #pragma unroll
        for (int kk = 0; kk < 16; ++kk) {
            float4 a4 = *(float4*)&As[kk][ty * 4];
            float4 b4 = *(float4*)&Bs[kk][tx * 4];
            float ar[4] = {a4.x, a4.y, a4.z, a4.w};
            float br[4] = {b4.x, b4.y, b4.z, b4.w};
            #pragma unroll
            for (int i = 0; i < 4; ++i)
                #pragma unroll
                for (int j = 0; j < 4; ++j)
                    c[i][j] = fmaf(ar[i], br[j], c[i][j]);
        }
        __syncthreads();
    }
    #pragma unroll
    for (int i = 0; i < 4; ++i) {
        float4 v = make_float4(c[i][0], c[i][1], c[i][2], c[i][3]);
        *(float4*)(C + (long)(m0 + ty * 4 + i) * N + n0 + tx * 4) = v;
    }
}

// attn[b,i,j] = tanh( mask_j * (qp[b,i,:]·kp[b,j,:] + qf2[b,i,:]·kf2[b,j,:]) / temp )
__global__ __launch_bounds__(256) void attn_fused(const float* __restrict__ qp, const float* __restrict__ kp,
                                                  const float* __restrict__ qf2, const float* __restrict__ kf2,
                                                  const int* __restrict__ lens, float* __restrict__ attn)
{
    __shared__ float As[16][68];
    __shared__ float Bs[16][68];
    const int b = blockIdx.z;
    const int len = lens[b];
    const long off = (long)b * PLANE;
    const int m0 = blockIdx.y * 64, n0 = blockIdx.x * 64;
    const int tid = threadIdx.x, tx = tid & 15, ty = tid >> 4;
    const int arow = tid >> 2, ac4 = (tid & 3) * 4;
    float c[4][4] = {};
    const float* Aps[2] = {qp + off, qf2 + off};
    const float* Bps[2] = {kp + off, kf2 + off};
    for (int p = 0; p < 2; ++p) {
        const float* Ap = Aps[p];
        const float* Bp = Bps[p];
        for (int k0 = 0; k0 < D_; k0 += 16) {
            float4 av = *(const float4*)(Ap + (long)(m0 + arow) * D_ + k0 + ac4);
            float4 bv = *(const float4*)(Bp + (long)(n0 + arow) * D_ + k0 + ac4);
            As[ac4 + 0][arow] = av.x; As[ac4 + 1][arow] = av.y;
            As[ac4 + 2][arow] = av.z; As[ac4 + 3][arow] = av.w;
            Bs[ac4 + 0][arow] = bv.x; Bs[ac4 + 1][arow] = bv.y;
            Bs[ac4 + 2][arow] = bv.z; Bs[ac4 + 3][arow] = bv.w;
            __syncthreads();
            #pragma unroll
            for (int kk = 0; kk < 16; ++kk) {
                float4 a4 = *(float4*)&As[kk][ty * 4];
                float4 b4 = *(float4*)&Bs[kk][tx * 4];
                float ar[4] = {a4.x, a4.y, a4.z, a4.w};
                float br[4] = {b4.x, b4.y, b4.z, b4.w};
                #pragma unroll
                for (int i = 0; i < 4; ++i)
                    #pragma unroll
                    for (int j = 0; j < 4; ++j)
                        c[i][j] = fmaf(ar[i], br[j], c[i][j]);
            }
            __syncthreads();
        }
    }
    #pragma unroll
    for (int i = 0; i < 4; ++i) {
        float r[4];
        #pragma unroll
        for (int j = 0; j < 4; ++j) {
            int col = n0 + tx * 4 + j;
            float vv = c[i][j] * INV_TEMP;
            r[j] = (col < len) ? tanhf(vv) : 0.0f;
        }
        float4 v = make_float4(r[0], r[1], r[2], r[3]);
        *(float4*)(attn + ((long)b * L_ + m0 + ty * 4 + i) * L_ + n0 + tx * 4) = v;
    }
}

// feat_attn[b,i,:] = softmax_j( sum_f |xf[b,i,f]-xf[b,j,f]| * imp[f], masked j>=len -> -1e9 )
__global__ __launch_bounds__(256) void feat_kernel(const float* __restrict__ x, const float* __restrict__ imp,
                                                   const int* __restrict__ lens, float* __restrict__ fa)
{
    __shared__ float xfs[L_ * NF]; // 22.5 KB
    const int b = blockIdx.y;
    const int i0 = blockIdx.x * 16;
    const int tid = threadIdx.x;
    for (int idx = tid; idx < L_ * NF; idx += 256) {
        int j = idx / NF, f = idx - j * NF;
        xfs[idx] = x[((long)b * L_ + j) * D_ + f];
    }
    float im[NF];
    #pragma unroll
    for (int f = 0; f < NF; ++f) im[f] = imp[f];
    const int len = lens[b];
    __syncthreads();
    const int wave = tid >> 6, lane = tid & 63;
    for (int r = 0; r < 4; ++r) {
        const int i = i0 + wave * 4 + r;
        float xi[NF];
        #pragma unroll
        for (int f = 0; f < NF; ++f) xi[f] = xfs[i * NF + f];
        float l[8];
        float m = -INFINITY;
        #pragma unroll
        for (int t = 0; t < 8; ++t) {
            int j = lane + t * 64;
            float s = 0.f;
            #pragma unroll
            for (int f = 0; f < NF; ++f) s = fmaf(fabsf(xi[f] - xfs[j * NF + f]), im[f], s);
            s = (j < len) ? s : NEGV;
            l[t] = s;
            m = fmaxf(m, s);
        }
        #pragma unroll
        for (int o = 32; o >= 1; o >>= 1) m = fmaxf(m, __shfl_xor(m, o));
        float ssum = 0.f;
        #pragma unroll
        for (int t = 0; t < 8; ++t) { l[t] = expf(l[t] - m); ssum += l[t]; }
        #pragma unroll
        for (int o = 32; o >= 1; o >>= 1) ssum += __shfl_xor(ssum, o);
        float inv = 1.0f / ssum;
        #pragma unroll
        for (int t = 0; t < 8; ++t)
            fa[((long)b * L_ + i) * L_ + lane + t * 64] = l[t] * inv;
    }
}

// out = LN(xin + res) * gamma + beta, one wave per row of 512
__global__ __launch_bounds__(64) void ln_kernel(const float* __restrict__ xin, const float* __restrict__ res,
                                                const float* __restrict__ gamma, const float* __restrict__ beta,
                                                float* __restrict__ out)
{
    const long row = blockIdx.x;
    const int lane = threadIdx.x;
    float v[8];
    float s = 0.f, ss = 0.f;
    #pragma unroll
    for (int t = 0; t < 8; ++t) {
        float u = xin[row * D_ + lane + t * 64] + res[row * D_ + lane + t * 64];
        v[t] = u; s += u; ss = fmaf(u, u, ss);
    }
    #pragma unroll
    for (int o = 32; o >= 1; o >>= 1) { s += __shfl_xor(s, o); ss += __shfl_xor(ss, o); }
    const float mu = s * (1.0f / D_);
    const float var = ss * (1.0f / D_) - mu * mu;
    const float inv = 1.0f / sqrtf(var + 1e-6f);
    #pragma unroll
    for (int t = 0; t < 8; ++t) {
        int d = lane + t * 64;
        out[row * D_ + d] = (v[t] - mu) * inv * gamma[d] + beta[d];
    }
}

extern "C" void kernel_launch(void* const* d_in, const int* in_sizes, int n_in,
                              void* d_out, int out_size, void* d_ws, size_t ws_size,
                              hipStream_t stream) {
    const float* q     = (const float*)d_in[0];
    const float* k     = (const float*)d_in[1];
    const float* v     = (const float*)d_in[2];
    const float* x     = (const float*)d_in[3];
    const int*   lens  = (const int*)d_in[4];
    const float* Wq    = (const float*)d_in[5];
    const float* Wk    = (const float*)d_in[6];
    const float* Wv    = (const float*)d_in[7];
    const float* Wqf   = (const float*)d_in[8];
    const float* Wkf   = (const float*)d_in[9];
    const float* Wfc   = (const float*)d_in[10];
    const float* imp   = (const float*)d_in[11];
    const float* gamma = (const float*)d_in[12];
    const float* beta  = (const float*)d_in[13];

    float* out  = (float*)d_out;          // [B,L,D]
    float* attn = out + OUT_ELEMS;        // [B,L,L]

    float* ws   = (float*)d_ws;
    float* buf0 = ws;                     // 8 MB each
    float* buf1 = ws + 1 * OUT_ELEMS;
    float* buf2 = ws + 2 * OUT_ELEMS;
    float* buf3 = ws + 3 * OUT_ELEMS;
    float* buf4 = ws + 4 * OUT_ELEMS;     // peak ws use: 40 MB

    dim3 gProj(8, 64, 1); // N/64 x M/64, M=4096
    dim3 gBat(8, 8, 8);   // per-batch 512x512

    // Phase 1: feature path first (lets qf/kf buffers be reused for qp/kp)
    gemm64<true><<<gProj, 256, 0, stream>>>(q, Wqf, buf0, 4096, 512, 512, 0, 0, 0);  // qf
    gemm64<true><<<gProj, 256, 0, stream>>>(k, Wkf, buf1, 4096, 512, 512, 0, 0, 0);  // kf
    feat_kernel<<<dim3(32, 8), 256, 0, stream>>>(x, imp, lens, buf2);                // feat_attn
    gemm64<false><<<gBat, 256, 0, stream>>>(buf2, buf0, buf3, 512, 512, 512, PLANE, PLANE, PLANE); // qf2
    gemm64<false><<<gBat, 256, 0, stream>>>(buf2, buf1, buf4, 512, 512, 512, PLANE, PLANE, PLANE); // kf2

    // Phase 2: main projections (reuse buf0..buf2)
    gemm64<true><<<gProj, 256, 0, stream>>>(q, Wq, buf0, 4096, 512, 512, 0, 0, 0);   // qp
    gemm64<true><<<gProj, 256, 0, stream>>>(k, Wk, buf1, 4096, 512, 512, 0, 0, 0);   // kp
    gemm64<true><<<gProj, 256, 0, stream>>>(v, Wv, buf2, 4096, 512, 512, 0, 0, 0);   // vp

    // Phase 3: attention scores (fused two products + mask + tanh) -> output 1
    attn_fused<<<gBat, 256, 0, stream>>>(buf0, buf1, buf3, buf4, lens, attn);

    // Phase 4: out1 = attn @ vp ; out2 = out1 @ Wfc^T ; LN(out2 + q) -> output 0
    gemm64<false><<<gBat, 256, 0, stream>>>(attn, buf2, buf0, 512, 512, 512, (long)L_ * L_, PLANE, PLANE);
    gemm64<true><<<gProj, 256, 0, stream>>>(buf0, Wfc, buf1, 4096, 512, 512, 0, 0, 0);
    ln_kernel<<<dim3(4096), 64, 0, stream>>>(buf1, q, gamma, beta, out);
}

// Round 2
// 222.014 us; speedup vs baseline: 2.2799x; 2.2799x over previous
//
#include <hip/hip_runtime.h>
#include <math.h>

typedef __bf16 bf16x8 __attribute__((ext_vector_type(8)));
typedef __bf16 bf16x4 __attribute__((ext_vector_type(4)));
typedef float  f32x4  __attribute__((ext_vector_type(4)));

namespace {
constexpr int B_ = 8, L_ = 512, D_ = 512, NF = 11;
constexpr long WE = (long)L_ * L_;     // 262144 elems (one 512x512 plane)
constexpr long NE = (long)B_ * WE;     // 2097152 elems (B*L*D)
constexpr float NEGV = -1.0e9f;
constexpr float INV_TEMP = 0.044194173824159216f; // 1/sqrt(512)
enum { EPI_BF16N = 0, EPI_F32N = 1, EPI_SCORES = 2, EPI_PROJ = 3 };
}

typedef __attribute__((address_space(1))) void gv_t;
typedef __attribute__((address_space(3))) void lv_t;

__device__ __forceinline__ void async_cp16(const void* g, void* l) {
  __builtin_amdgcn_global_load_lds((gv_t*)g, (lv_t*)l, 16, 0, 0);
}

// C = A * B^T, A [M,K] row-major, B [N,K] row-major, both bf16, fp32 accum.
// 128x128 block tile, BK=32, 256 threads (4 waves, 2x2 of 64x64 wave tiles).
// blockIdx.z decomposed as zb=z&7 (batch), zs=z>>3 (selector), with element
// strides sAb/sAs etc. EPI_PROJ uses its own z mapping (5 fused projections).
template<int EPI, bool DUAL>
__global__ __launch_bounds__(256)
void gemm_nt(const __bf16* __restrict__ A, const __bf16* __restrict__ B,
             const __bf16* __restrict__ A2, const __bf16* __restrict__ B2,
             float* __restrict__ Cf, __bf16* __restrict__ Cb,
             const int* __restrict__ lens,
             int M, int N, int K,
             long sAb, long sAs, long sBb, long sBs, long sCb, long sCs)
{
  __shared__ __align__(16) __bf16 sA[128 * 32];
  __shared__ __align__(16) __bf16 sB[128 * 32];

  const int bz = blockIdx.z;
  long cOff;
  int len = 0;
  if (EPI == EPI_PROJ) {
    // z: 0=qp(q,Wq) 1=kp(k,Wk) 2=qfT(q,Wqf) 3=kfT(k,Wkf) 4=vpT(v,Wv)
    A += (long)(bz < 2 ? bz : bz - 2) * sAb;
    B += (long)bz * sBb;
    cOff = (long)bz * sCb;
  } else {
    const int zb = bz & 7, zs = bz >> 3;
    A += (long)zb * sAb + (long)zs * sAs;
    B += (long)zb * sBb + (long)zs * sBs;
    cOff = (long)zb * sCb + (long)zs * sCs;
    if (DUAL) { A2 += (long)zb * sAb; B2 += (long)zb * sBb; }
    if (EPI == EPI_SCORES) len = lens[zb];
  }

  const int tid = threadIdx.x;
  const int m0 = blockIdx.y * 128, n0 = blockIdx.x * 128;
  // staging: each thread moves 16B; row = tid>>2 (and +64), chunk = (tid&3)*8 elems
  const int srow = tid >> 2, scol = (tid & 3) * 8;
  __bf16* lA0 = sA + srow * 32 + scol;
  __bf16* lB0 = sB + srow * 32 + scol;
  const int wave = tid >> 6, lane = tid & 63;
  const int quad = lane >> 4, l16 = lane & 15;
  const int wm = (wave >> 1) * 64, wn = (wave & 1) * 64;
  const __bf16* rA = sA + (wm + l16) * 32 + quad * 8;
  const __bf16* rB = sB + (wn + l16) * 32 + quad * 8;

  f32x4 acc[4][4];
  #pragma unroll
  for (int i = 0; i < 4; ++i)
    #pragma unroll
    for (int j = 0; j < 4; ++j) acc[i][j] = 0.0f;

  const int passes = DUAL ? 2 : 1;
  for (int p = 0; p < passes; ++p) {
    const __bf16* Ap = (DUAL && p) ? A2 : A;
    const __bf16* Bp = (DUAL && p) ? B2 : B;
    const __bf16* ga = Ap + (long)(m0 + srow) * K + scol;
    const __bf16* gb = Bp + (long)(n0 + srow) * K + scol;
    for (int k0 = 0; k0 < K; k0 += 32) {
      __syncthreads();                       // previous tile's reads done
      async_cp16(ga + k0, lA0);
      async_cp16(ga + (long)64 * K + k0, lA0 + 64 * 32);
      async_cp16(gb + k0, lB0);
      async_cp16(gb + (long)64 * K + k0, lB0 + 64 * 32);
      __syncthreads();                       // drains vmcnt before LDS reads
      bf16x8 af[4], bfr[4];
      #pragma unroll
      for (int i = 0; i < 4; ++i) af[i]  = *(const bf16x8*)(rA + i * 16 * 32);
      #pragma unroll
      for (int j = 0; j < 4; ++j) bfr[j] = *(const bf16x8*)(rB + j * 16 * 32);
      #pragma unroll
      for (int i = 0; i < 4; ++i)
        #pragma unroll
        for (int j = 0; j < 4; ++j)
          acc[i][j] = __builtin_amdgcn_mfma_f32_16x16x32_bf16(af[i], bfr[j], acc[i][j], 0, 0, 0);
    }
  }

  // C/D layout: col(n) = lane&15, row(m) = quad*4 + reg   [m89-verified]
  #pragma unroll
  for (int i = 0; i < 4; ++i) {
    const int mb = m0 + wm + i * 16 + quad * 4;
    #pragma unroll
    for (int j = 0; j < 4; ++j) {
      const int nn = n0 + wn + j * 16 + l16;
      f32x4 c = acc[i][j];
      if (EPI == EPI_BF16N) {
        #pragma unroll
        for (int r = 0; r < 4; ++r)
          Cb[cOff + (long)(mb + r) * N + nn] = (__bf16)c[r];
      } else if (EPI == EPI_F32N) {
        #pragma unroll
        for (int r = 0; r < 4; ++r)
          Cf[cOff + (long)(mb + r) * N + nn] = c[r];
      } else if (EPI == EPI_SCORES) {
        #pragma unroll
        for (int r = 0; r < 4; ++r) {
          float v = c[r] * INV_TEMP;
          v = (nn < len) ? tanhf(v) : 0.0f;
          Cf[cOff + (long)(mb + r) * N + nn] = v;       // attn fp32 (output 1)
          Cb[cOff + (long)(mb + r) * N + nn] = (__bf16)v; // attn bf16 (for attn@vp)
        }
      } else { // EPI_PROJ
        if (bz < 2) {
          #pragma unroll
          for (int r = 0; r < 4; ++r)
            Cb[cOff + (long)(mb + r) * N + nn] = (__bf16)c[r];
        } else {
          // transposed per-batch: T[b][n][l], b = m>>9, l = m&511
          const long bb = (long)(mb >> 9) << 18;
          const int l = mb & 511;
          bf16x4 pk;
          pk[0] = (__bf16)c[0]; pk[1] = (__bf16)c[1];
          pk[2] = (__bf16)c[2]; pk[3] = (__bf16)c[3];
          *(bf16x4*)(Cb + cOff + bb + (long)nn * 512 + l) = pk;
        }
      }
    }
  }
}

// fp32 -> bf16 conversion, one array per blockIdx.y
struct CvtArgs { const float* s[9]; __bf16* d[9]; int n[9]; };
__global__ __launch_bounds__(256) void cvt_kernel(CvtArgs a)
{
  const int id = blockIdx.y;
  const float* __restrict__ s = a.s[id];
  __bf16* __restrict__ d = a.d[id];
  const int n = a.n[id];
  for (long i = (long)(blockIdx.x * 256 + threadIdx.x) * 4; i < n; i += (long)gridDim.x * 1024) {
    float4 v = *(const float4*)(s + i);
    bf16x4 o;
    o[0] = (__bf16)v.x; o[1] = (__bf16)v.y; o[2] = (__bf16)v.z; o[3] = (__bf16)v.w;
    *(bf16x4*)(d + i) = o;
  }
}

// feat_attn[b,i,:] = softmax_j( sum_f |xf[b,i,f]-xf[b,j,f]| * imp[f], j>=len -> -1e9 ), bf16 out
__global__ __launch_bounds__(256) void feat_kernel(const float* __restrict__ x, const float* __restrict__ imp,
                                                   const int* __restrict__ lens, __bf16* __restrict__ fa)
{
    __shared__ float xfs[L_ * NF]; // 22.5 KB
    const int b = blockIdx.y;
    const int i0 = blockIdx.x * 16;
    const int tid = threadIdx.x;
    for (int idx = tid; idx < L_ * NF; idx += 256) {
        int j = idx / NF, f = idx - j * NF;
        xfs[idx] = x[((long)b * L_ + j) * D_ + f];
    }
    float im[NF];
    #pragma unroll
    for (int f = 0; f < NF; ++f) im[f] = imp[f];
    const int len = lens[b];
    __syncthreads();
    const int wave = tid >> 6, lane = tid & 63;
    for (int r = 0; r < 4; ++r) {
        const int i = i0 + wave * 4 + r;
        float xi[NF];
        #pragma unroll
        for (int f = 0; f < NF; ++f) xi[f] = xfs[i * NF + f];
        float l[8];
        float m = -INFINITY;
        #pragma unroll
        for (int t = 0; t < 8; ++t) {
            int j = lane + t * 64;
            float s = 0.f;
            #pragma unroll
            for (int f = 0; f < NF; ++f) s = fmaf(fabsf(xi[f] - xfs[j * NF + f]), im[f], s);
            s = (j < len) ? s : NEGV;
            l[t] = s;
            m = fmaxf(m, s);
        }
        #pragma unroll
        for (int o = 32; o >= 1; o >>= 1) m = fmaxf(m, __shfl_xor(m, o));
        float ssum = 0.f;
        #pragma unroll
        for (int t = 0; t < 8; ++t) { l[t] = expf(l[t] - m); ssum += l[t]; }
        #pragma unroll
        for (int o = 32; o >= 1; o >>= 1) ssum += __shfl_xor(ssum, o);
        float inv = 1.0f / ssum;
        #pragma unroll
        for (int t = 0; t < 8; ++t)
            fa[((long)b * L_ + i) * L_ + lane + t * 64] = (__bf16)(l[t] * inv);
    }
}

// out = LN(xin + res) * gamma + beta, one wave per row of 512
__global__ __launch_bounds__(64) void ln_kernel(const float* __restrict__ xin, const float* __restrict__ res,
                                                const float* __restrict__ gamma, const float* __restrict__ beta,
                                                float* __restrict__ out)
{
    const long row = blockIdx.x;
    const int lane = threadIdx.x;
    float v[8];
    float s = 0.f, ss = 0.f;
    #pragma unroll
    for (int t = 0; t < 8; ++t) {
        float u = xin[row * D_ + lane + t * 64] + res[row * D_ + lane + t * 64];
        v[t] = u; s += u; ss = fmaf(u, u, ss);
    }
    #pragma unroll
    for (int o = 32; o >= 1; o >>= 1) { s += __shfl_xor(s, o); ss += __shfl_xor(ss, o); }
    const float mu = s * (1.0f / D_);
    const float var = ss * (1.0f / D_) - mu * mu;
    const float inv = 1.0f / sqrtf(var + 1e-6f);
    #pragma unroll
    for (int t = 0; t < 8; ++t) {
        int d = lane + t * 64;
        out[row * D_ + d] = (v[t] - mu) * inv * gamma[d] + beta[d];
    }
}

extern "C" void kernel_launch(void* const* d_in, const int* in_sizes, int n_in,
                              void* d_out, int out_size, void* d_ws, size_t ws_size,
                              hipStream_t stream) {
    const float* q     = (const float*)d_in[0];
    const float* k     = (const float*)d_in[1];
    const float* v     = (const float*)d_in[2];
    const float* x     = (const float*)d_in[3];
    const int*   lens  = (const int*)d_in[4];
    const float* Wq    = (const float*)d_in[5];
    const float* Wk    = (const float*)d_in[6];
    const float* Wv    = (const float*)d_in[7];
    const float* Wqf   = (const float*)d_in[8];
    const float* Wkf   = (const float*)d_in[9];
    const float* Wfc   = (const float*)d_in[10];
    const float* imp   = (const float*)d_in[11];
    const float* gamma = (const float*)d_in[12];
    const float* beta  = (const float*)d_in[13];

    constexpr long MB = 1 << 20;
    char* w = (char*)d_ws;
    __bf16* qb    = (__bf16*)(w);            // q,k,v bf16: 3 x NE (0..12MB)
    __bf16* Wb    = (__bf16*)(w + 12 * MB);  // [Wq,Wk,Wqf,Wkf,Wv,Wfc]: 6 x WE (12..15MB)
    __bf16* qp_b  = (__bf16*)(w + 15 * MB);  // [qp,kp,qfT,kfT,vpT]: 5 x NE (15..35MB)
    __bf16* featb = (__bf16*)(w + 35 * MB);  // feat_attn bf16 (35..39MB)
    __bf16* attnb = (__bf16*)(w + 23 * MB);  // reuse qfT slot (free after featmm)
    __bf16* out1b = (__bf16*)(w + 27 * MB);  // reuse kfT slot
    float*  out2  = (float*)(w);             // reuse qb+kb (free after proj)

    float*  outp  = (float*)d_out;           // output 0 [B,L,D]
    float*  attnf = outp + NE;               // output 1 [B,L,L]
    __bf16* qf2b  = (__bf16*)d_out;          // qf2,kf2 bf16 scratch in out-region (overwritten by LN later)

    // 1) fp32 -> bf16
    CvtArgs ca;
    ca.s[0] = q;   ca.d[0] = qb;           ca.n[0] = (int)NE;
    ca.s[1] = k;   ca.d[1] = qb + NE;      ca.n[1] = (int)NE;
    ca.s[2] = v;   ca.d[2] = qb + 2 * NE;  ca.n[2] = (int)NE;
    ca.s[3] = Wq;  ca.d[3] = Wb;           ca.n[3] = (int)WE;
    ca.s[4] = Wk;  ca.d[4] = Wb + WE;      ca.n[4] = (int)WE;
    ca.s[5] = Wqf; ca.d[5] = Wb + 2 * WE;  ca.n[5] = (int)WE;
    ca.s[6] = Wkf; ca.d[6] = Wb + 3 * WE;  ca.n[6] = (int)WE;
    ca.s[7] = Wv;  ca.d[7] = Wb + 4 * WE;  ca.n[7] = (int)WE;
    ca.s[8] = Wfc; ca.d[8] = Wb + 5 * WE;  ca.n[8] = (int)WE;
    cvt_kernel<<<dim3(512, 9), 256, 0, stream>>>(ca);

    // 2) 5 projections fused: qp,kp normal; qfT,kfT,vpT transposed (640 blocks)
    gemm_nt<EPI_PROJ, false><<<dim3(4, 32, 5), 256, 0, stream>>>(
        qb, Wb, nullptr, nullptr, nullptr, qp_b, nullptr,
        4096, 512, 512, NE, 0, WE, 0, NE, 0);

    // 3) feature-distance softmax -> bf16
    feat_kernel<<<dim3(32, 8), 256, 0, stream>>>(x, imp, lens, featb);

    // 4) qf2 = feat@qf, kf2 = feat@kf (256 blocks; zb=batch, zs=qf/kf)
    gemm_nt<EPI_BF16N, false><<<dim3(4, 4, 16), 256, 0, stream>>>(
        featb, qp_b + 2 * NE, nullptr, nullptr, nullptr, qf2b, nullptr,
        512, 512, 512, WE, 0, WE, NE, WE, NE);

    // 5) attn = tanh(mask((qp.kp^T + qf2.kf2^T)/temp)) -> fp32 out + bf16 scratch
    gemm_nt<EPI_SCORES, true><<<dim3(4, 4, 8), 256, 0, stream>>>(
        qp_b, qp_b + NE, qf2b, qf2b + NE, attnf, attnb, lens,
        512, 512, 512, WE, 0, WE, 0, WE, 0);

    // 6) out1 = attn @ vp  (via vpT, NT)
    gemm_nt<EPI_BF16N, false><<<dim3(4, 4, 8), 256, 0, stream>>>(
        attnb, qp_b + 4 * NE, nullptr, nullptr, nullptr, out1b, nullptr,
        512, 512, 512, WE, 0, WE, 0, WE, 0);

    // 7) out2 = out1 @ Wfc^T (fp32 out)
    gemm_nt<EPI_F32N, false><<<dim3(4, 32, 1), 256, 0, stream>>>(
        out1b, Wb + 5 * WE, nullptr, nullptr, out2, nullptr, nullptr,
        4096, 512, 512, 0, 0, 0, 0, 0, 0);

    // 8) LayerNorm(out2 + q)
    ln_kernel<<<4096, 64, 0, stream>>>(out2, q, gamma, beta, outp);
}

// Round 3
// 187.478 us; speedup vs baseline: 2.6999x; 1.1842x over previous
//
#include <hip/hip_runtime.h>
#include <math.h>

typedef __bf16 bf16x8 __attribute__((ext_vector_type(8)));
typedef __bf16 bf16x4 __attribute__((ext_vector_type(4)));
typedef float  f32x4  __attribute__((ext_vector_type(4)));

namespace {
constexpr int L_ = 512, D_ = 512, NF = 11;
constexpr long WE = (long)L_ * L_;   // 262144 elems, one 512x512 plane
constexpr long NE = 8 * WE;          // 2097152 elems, B*L*D
constexpr long CPL = 512L * 1024;    // concatenated plane elems (512 rows x 1024)
constexpr float NEGV = -1.0e9f;
constexpr float INV_TEMP = 0.044194173824159216f; // 1/sqrt(512)
}

typedef __attribute__((address_space(1))) void gv_t;
typedef __attribute__((address_space(3))) void lv_t;

__device__ __forceinline__ void async_cp16(const void* g, void* l) {
  __builtin_amdgcn_global_load_lds((gv_t*)g, (lv_t*)l, 16, 0, 0);
}

// ---------------- 128x128 projection kernel (M=4096, N=K=512) ----------------
// z: 0=qp->qcat[:,0:512]  1=kp->kcat[:,0:512]  2=qfT  3=kfT  4=vp (normal)
__global__ __launch_bounds__(256)
void proj_kernel(const __bf16* __restrict__ qkv, const __bf16* __restrict__ Wb,
                 __bf16* __restrict__ qcat, __bf16* __restrict__ kcat,
                 __bf16* __restrict__ qfkfT, __bf16* __restrict__ vpb)
{
  __shared__ __align__(16) __bf16 sA[128 * 32];
  __shared__ __align__(16) __bf16 sB[128 * 32];
  const int z = blockIdx.z;
  const __bf16* A = qkv + (long)((z == 4) ? 2 : (z & 1)) * NE;
  const __bf16* B = Wb + (long)z * WE;

  const int tid = threadIdx.x;
  const int m0 = blockIdx.y * 128, n0 = blockIdx.x * 128;
  const int srow = tid >> 2, scol = (tid & 3) * 8;
  __bf16* lA0 = sA + srow * 32 + scol;
  __bf16* lB0 = sB + srow * 32 + scol;
  const int wave = tid >> 6, lane = tid & 63;
  const int quad = lane >> 4, l16 = lane & 15;
  const int wm = (wave >> 1) * 64, wn = (wave & 1) * 64;
  const __bf16* rA = sA + (wm + l16) * 32 + quad * 8;
  const __bf16* rB = sB + (wn + l16) * 32 + quad * 8;

  f32x4 acc[4][4];
  #pragma unroll
  for (int i = 0; i < 4; ++i)
    #pragma unroll
    for (int j = 0; j < 4; ++j) acc[i][j] = 0.0f;

  const __bf16* ga = A + (long)(m0 + srow) * 512 + scol;
  const __bf16* gb = B + (long)(n0 + srow) * 512 + scol;
  for (int k0 = 0; k0 < 512; k0 += 32) {
    __syncthreads();
    async_cp16(ga + k0, lA0);
    async_cp16(ga + 64 * 512 + k0, lA0 + 64 * 32);
    async_cp16(gb + k0, lB0);
    async_cp16(gb + 64 * 512 + k0, lB0 + 64 * 32);
    __syncthreads();
    bf16x8 af[4], bfr[4];
    #pragma unroll
    for (int i = 0; i < 4; ++i) af[i]  = *(const bf16x8*)(rA + i * 16 * 32);
    #pragma unroll
    for (int j = 0; j < 4; ++j) bfr[j] = *(const bf16x8*)(rB + j * 16 * 32);
    #pragma unroll
    for (int i = 0; i < 4; ++i)
      #pragma unroll
      for (int j = 0; j < 4; ++j)
        acc[i][j] = __builtin_amdgcn_mfma_f32_16x16x32_bf16(af[i], bfr[j], acc[i][j], 0, 0, 0);
  }

  // C/D: col = lane&15 (+tile offsets), row = quad*4 + reg
  #pragma unroll
  for (int i = 0; i < 4; ++i) {
    const int mb = m0 + wm + i * 16 + quad * 4;
    #pragma unroll
    for (int j = 0; j < 4; ++j) {
      const int nn = n0 + wn + j * 16 + l16;
      f32x4 c = acc[i][j];
      if (z < 2) {
        __bf16* C = (z == 0) ? qcat : kcat;
        #pragma unroll
        for (int r = 0; r < 4; ++r)
          C[(long)(mb + r) * 1024 + nn] = (__bf16)c[r];
      } else if (z == 4) {
        #pragma unroll
        for (int r = 0; r < 4; ++r)
          vpb[(long)(mb + r) * 512 + nn] = (__bf16)c[r];
      } else {
        __bf16* T = qfkfT + (long)(z - 2) * NE;
        const long bb = (long)(mb >> 9) << 18; // batch plane (512*512)
        const int l = mb & 511;
        bf16x4 pk;
        pk[0] = (__bf16)c[0]; pk[1] = (__bf16)c[1];
        pk[2] = (__bf16)c[2]; pk[3] = (__bf16)c[3];
        *(bf16x4*)(T + bb + (long)nn * 512 + l) = pk;
      }
    }
  }
}

// ---------------- 64x128 batched NT core (M=N=512) ----------------
// A [512,K] row-major (stride K), B [512,K] row-major (stride K), fp32 acc.
// 256 threads = 4 waves in 2x2 of 32x64 wave tiles.
__device__ __forceinline__ void core64(const __bf16* __restrict__ A,
                                       const __bf16* __restrict__ B, int K,
                                       __bf16* sA, __bf16* sB, f32x4 (&acc)[2][4])
{
  const int tid = threadIdx.x;
  const int m0 = blockIdx.y * 64, n0 = blockIdx.x * 128;
  const int srow = tid >> 2, scol = (tid & 3) * 8;
  __bf16* lA0 = sA + srow * 32 + scol;
  __bf16* lB0 = sB + srow * 32 + scol;
  const int wave = tid >> 6, lane = tid & 63;
  const int quad = lane >> 4, l16 = lane & 15;
  const int wm = (wave >> 1) * 32, wn = (wave & 1) * 64;
  const __bf16* rA = sA + (wm + l16) * 32 + quad * 8;
  const __bf16* rB = sB + (wn + l16) * 32 + quad * 8;
  const __bf16* ga = A + (long)(m0 + srow) * K + scol;
  const __bf16* gb = B + (long)(n0 + srow) * K + scol;
  for (int k0 = 0; k0 < K; k0 += 32) {
    __syncthreads();
    async_cp16(ga + k0, lA0);                       // A tile 64x32 (srow<64 covers all 256 thr)
    async_cp16(gb + k0, lB0);                       // B tile rows 0..63
    async_cp16(gb + (long)64 * K + k0, lB0 + 64 * 32); // B rows 64..127
    __syncthreads();
    bf16x8 af[2], bfr[4];
    #pragma unroll
    for (int i = 0; i < 2; ++i) af[i]  = *(const bf16x8*)(rA + i * 16 * 32);
    #pragma unroll
    for (int j = 0; j < 4; ++j) bfr[j] = *(const bf16x8*)(rB + j * 16 * 32);
    #pragma unroll
    for (int i = 0; i < 2; ++i)
      #pragma unroll
      for (int j = 0; j < 4; ++j)
        acc[i][j] = __builtin_amdgcn_mfma_f32_16x16x32_bf16(af[i], bfr[j], acc[i][j], 0, 0, 0);
  }
}

// mega2: z 0..7 qf2=feat@qf -> qcat[:,512:], z 8..15 kf2 -> kcat[:,512:],
//        z 16..23 vp2T[b] = Wfc . vp[b]^T  (i.e. NT(Wfc, vp[b]))
__global__ __launch_bounds__(256)
void mega2_kernel(const __bf16* __restrict__ featb, const __bf16* __restrict__ qfkfT,
                  const __bf16* __restrict__ Wfcb, const __bf16* __restrict__ vpb,
                  __bf16* __restrict__ qcat, __bf16* __restrict__ kcat,
                  __bf16* __restrict__ vp2T)
{
  __shared__ __align__(16) __bf16 sA[64 * 32];
  __shared__ __align__(16) __bf16 sB[128 * 32];
  const int z = blockIdx.z;
  const __bf16 *A, *B;
  __bf16* C;
  int ldc;
  if (z < 16) {
    const int b = z & 7, s = z >> 3;
    A = featb + (long)b * WE;
    B = qfkfT + (long)s * NE + (long)b * WE;
    C = (s ? kcat : qcat) + (long)b * CPL + 512;
    ldc = 1024;
  } else {
    const int b = z - 16;
    A = Wfcb;
    B = vpb + (long)b * WE;
    C = vp2T + (long)b * WE;
    ldc = 512;
  }
  f32x4 acc[2][4];
  #pragma unroll
  for (int i = 0; i < 2; ++i)
    #pragma unroll
    for (int j = 0; j < 4; ++j) acc[i][j] = 0.0f;
  core64(A, B, 512, sA, sB, acc);

  const int wave = threadIdx.x >> 6, lane = threadIdx.x & 63;
  const int quad = lane >> 4, l16 = lane & 15;
  const int wm = (wave >> 1) * 32, wn = (wave & 1) * 64;
  #pragma unroll
  for (int i = 0; i < 2; ++i) {
    const int mb = blockIdx.y * 64 + wm + i * 16 + quad * 4;
    #pragma unroll
    for (int j = 0; j < 4; ++j) {
      const int nn = blockIdx.x * 128 + wn + j * 16 + l16;
      f32x4 c = acc[i][j];
      #pragma unroll
      for (int r = 0; r < 4; ++r)
        C[(long)(mb + r) * ldc + nn] = (__bf16)c[r];
    }
  }
}

// scores: attn = tanh(mask((qcat . kcat^T)/temp)), K=1024 concatenated
__global__ __launch_bounds__(256)
void scores_kernel(const __bf16* __restrict__ qcat, const __bf16* __restrict__ kcat,
                   const int* __restrict__ lens, float* __restrict__ attnf,
                   __bf16* __restrict__ attnb)
{
  __shared__ __align__(16) __bf16 sA[64 * 32];
  __shared__ __align__(16) __bf16 sB[128 * 32];
  const int b = blockIdx.z;
  const int len = lens[b];
  f32x4 acc[2][4];
  #pragma unroll
  for (int i = 0; i < 2; ++i)
    #pragma unroll
    for (int j = 0; j < 4; ++j) acc[i][j] = 0.0f;
  core64(qcat + (long)b * CPL, kcat + (long)b * CPL, 1024, sA, sB, acc);

  const long off = (long)b * WE;
  const int wave = threadIdx.x >> 6, lane = threadIdx.x & 63;
  const int quad = lane >> 4, l16 = lane & 15;
  const int wm = (wave >> 1) * 32, wn = (wave & 1) * 64;
  #pragma unroll
  for (int i = 0; i < 2; ++i) {
    const int mb = blockIdx.y * 64 + wm + i * 16 + quad * 4;
    #pragma unroll
    for (int j = 0; j < 4; ++j) {
      const int nn = blockIdx.x * 128 + wn + j * 16 + l16;
      f32x4 c = acc[i][j];
      #pragma unroll
      for (int r = 0; r < 4; ++r) {
        float v = c[r] * INV_TEMP;
        v = (nn < len) ? tanhf(v) : 0.0f;
        attnf[off + (long)(mb + r) * 512 + nn] = v;
        attnb[off + (long)(mb + r) * 512 + nn] = (__bf16)v;
      }
    }
  }
}

// av2: out2[b] = attn[b] @ vp2[b]  (NT with vp2T), fp32 out
__global__ __launch_bounds__(256)
void av2_kernel(const __bf16* __restrict__ attnb, const __bf16* __restrict__ vp2T,
                float* __restrict__ out2)
{
  __shared__ __align__(16) __bf16 sA[64 * 32];
  __shared__ __align__(16) __bf16 sB[128 * 32];
  const int b = blockIdx.z;
  f32x4 acc[2][4];
  #pragma unroll
  for (int i = 0; i < 2; ++i)
    #pragma unroll
    for (int j = 0; j < 4; ++j) acc[i][j] = 0.0f;
  core64(attnb + (long)b * WE, vp2T + (long)b * WE, 512, sA, sB, acc);

  const long off = (long)b * WE;
  const int wave = threadIdx.x >> 6, lane = threadIdx.x & 63;
  const int quad = lane >> 4, l16 = lane & 15;
  const int wm = (wave >> 1) * 32, wn = (wave & 1) * 64;
  #pragma unroll
  for (int i = 0; i < 2; ++i) {
    const int mb = blockIdx.y * 64 + wm + i * 16 + quad * 4;
    #pragma unroll
    for (int j = 0; j < 4; ++j) {
      const int nn = blockIdx.x * 128 + wn + j * 16 + l16;
      f32x4 c = acc[i][j];
      #pragma unroll
      for (int r = 0; r < 4; ++r)
        out2[off + (long)(mb + r) * 512 + nn] = c[r];
    }
  }
}

// ---------------- fp32 -> bf16 conversion ----------------
struct CvtArgs { const float* s[9]; __bf16* d[9]; int n[9]; };
__global__ __launch_bounds__(256) void cvt_kernel(CvtArgs a)
{
  const int id = blockIdx.y;
  const float* __restrict__ s = a.s[id];
  __bf16* __restrict__ d = a.d[id];
  const int n = a.n[id];
  for (long i = (long)(blockIdx.x * 256 + threadIdx.x) * 4; i < n; i += (long)gridDim.x * 1024) {
    float4 v = *(const float4*)(s + i);
    bf16x4 o;
    o[0] = (__bf16)v.x; o[1] = (__bf16)v.y; o[2] = (__bf16)v.z; o[3] = (__bf16)v.w;
    *(bf16x4*)(d + i) = o;
  }
}

// ---------------- feature-distance softmax ----------------
__global__ __launch_bounds__(256) void feat_kernel(const float* __restrict__ x, const float* __restrict__ imp,
                                                   const int* __restrict__ lens, __bf16* __restrict__ fa)
{
    __shared__ float xfs[L_ * NF]; // 22.5 KB
    const int b = blockIdx.y;
    const int i0 = blockIdx.x * 16;
    const int tid = threadIdx.x;
    for (int idx = tid; idx < L_ * NF; idx += 256) {
        int j = idx / NF, f = idx - j * NF;
        xfs[idx] = x[((long)b * L_ + j) * D_ + f];
    }
    float im[NF];
    #pragma unroll
    for (int f = 0; f < NF; ++f) im[f] = imp[f];
    const int len = lens[b];
    __syncthreads();
    const int wave = tid >> 6, lane = tid & 63;
    for (int r = 0; r < 4; ++r) {
        const int i = i0 + wave * 4 + r;
        float xi[NF];
        #pragma unroll
        for (int f = 0; f < NF; ++f) xi[f] = xfs[i * NF + f];
        float l[8];
        float m = -INFINITY;
        #pragma unroll
        for (int t = 0; t < 8; ++t) {
            int j = lane + t * 64;
            float s = 0.f;
            #pragma unroll
            for (int f = 0; f < NF; ++f) s = fmaf(fabsf(xi[f] - xfs[j * NF + f]), im[f], s);
            s = (j < len) ? s : NEGV;
            l[t] = s;
            m = fmaxf(m, s);
        }
        #pragma unroll
        for (int o = 32; o >= 1; o >>= 1) m = fmaxf(m, __shfl_xor(m, o));
        float ssum = 0.f;
        #pragma unroll
        for (int t = 0; t < 8; ++t) { l[t] = expf(l[t] - m); ssum += l[t]; }
        #pragma unroll
        for (int o = 32; o >= 1; o >>= 1) ssum += __shfl_xor(ssum, o);
        float inv = 1.0f / ssum;
        #pragma unroll
        for (int t = 0; t < 8; ++t)
            fa[((long)b * L_ + i) * L_ + lane + t * 64] = (__bf16)(l[t] * inv);
    }
}

// ---------------- LayerNorm ----------------
__global__ __launch_bounds__(64) void ln_kernel(const float* __restrict__ xin, const float* __restrict__ res,
                                                const float* __restrict__ gamma, const float* __restrict__ beta,
                                                float* __restrict__ out)
{
    const long row = blockIdx.x;
    const int lane = threadIdx.x;
    float v[8];
    float s = 0.f, ss = 0.f;
    #pragma unroll
    for (int t = 0; t < 8; ++t) {
        float u = xin[row * D_ + lane + t * 64] + res[row * D_ + lane + t * 64];
        v[t] = u; s += u; ss = fmaf(u, u, ss);
    }
    #pragma unroll
    for (int o = 32; o >= 1; o >>= 1) { s += __shfl_xor(s, o); ss += __shfl_xor(ss, o); }
    const float mu = s * (1.0f / D_);
    const float var = ss * (1.0f / D_) - mu * mu;
    const float inv = 1.0f / sqrtf(var + 1e-6f);
    #pragma unroll
    for (int t = 0; t < 8; ++t) {
        int d = lane + t * 64;
        out[row * D_ + d] = (v[t] - mu) * inv * gamma[d] + beta[d];
    }
}

extern "C" void kernel_launch(void* const* d_in, const int* in_sizes, int n_in,
                              void* d_out, int out_size, void* d_ws, size_t ws_size,
                              hipStream_t stream) {
    const float* q     = (const float*)d_in[0];
    const float* k     = (const float*)d_in[1];
    const float* v     = (const float*)d_in[2];
    const float* x     = (const float*)d_in[3];
    const int*   lens  = (const int*)d_in[4];
    const float* Wq    = (const float*)d_in[5];
    const float* Wk    = (const float*)d_in[6];
    const float* Wv    = (const float*)d_in[7];
    const float* Wqf   = (const float*)d_in[8];
    const float* Wkf   = (const float*)d_in[9];
    const float* Wfc   = (const float*)d_in[10];
    const float* imp   = (const float*)d_in[11];
    const float* gamma = (const float*)d_in[12];
    const float* beta  = (const float*)d_in[13];

    constexpr long MB = 1 << 20;
    char* w = (char*)d_ws;
    __bf16* qkvb  = (__bf16*)(w);            //  0..12MB : q,k,v bf16
    __bf16* Wb    = (__bf16*)(w + 12 * MB);  // 12..15MB : Wq,Wk,Wqf,Wkf,Wv,Wfc
    __bf16* qfkfT = (__bf16*)(w + 15 * MB);  // 15..23MB : qfT,kfT
    __bf16* vpb   = (__bf16*)(w + 23 * MB);  // 23..27MB : vp
    __bf16* vp2T  = (__bf16*)(w + 27 * MB);  // 27..31MB : vp2T
    __bf16* qcat  = (__bf16*)(w + 31 * MB);  // 31..39MB : [qp | qf2] K=1024
    __bf16* kcat  = (__bf16*)(w + 39 * MB);  // 39..47MB : [kp | kf2]
    __bf16* attnb = (__bf16*)(w + 47 * MB);  // 47..51MB : attn bf16
    float*  out2  = (float*)(w + 51 * MB);   // 51..59MB : pre-LN fp32
    __bf16* featb = (__bf16*)(w + 59 * MB);  // 59..63MB : feat_attn bf16

    float*  outp  = (float*)d_out;           // output 0 [B,L,D]
    float*  attnf = outp + NE;               // output 1 [B,L,L]

    // 1) fp32 -> bf16
    CvtArgs ca;
    ca.s[0] = q;   ca.d[0] = qkvb;          ca.n[0] = (int)NE;
    ca.s[1] = k;   ca.d[1] = qkvb + NE;     ca.n[1] = (int)NE;
    ca.s[2] = v;   ca.d[2] = qkvb + 2 * NE; ca.n[2] = (int)NE;
    ca.s[3] = Wq;  ca.d[3] = Wb;            ca.n[3] = (int)WE;
    ca.s[4] = Wk;  ca.d[4] = Wb + WE;       ca.n[4] = (int)WE;
    ca.s[5] = Wqf; ca.d[5] = Wb + 2 * WE;   ca.n[5] = (int)WE;
    ca.s[6] = Wkf; ca.d[6] = Wb + 3 * WE;   ca.n[6] = (int)WE;
    ca.s[7] = Wv;  ca.d[7] = Wb + 4 * WE;   ca.n[7] = (int)WE;
    ca.s[8] = Wfc; ca.d[8] = Wb + 5 * WE;   ca.n[8] = (int)WE;
    cvt_kernel<<<dim3(512, 9), 256, 0, stream>>>(ca);

    // 2) feature-distance softmax (independent of projections)
    feat_kernel<<<dim3(32, 8), 256, 0, stream>>>(x, imp, lens, featb);

    // 3) 5 projections: qp->qcat, kp->kcat, qfT, kfT, vp (640 blocks)
    proj_kernel<<<dim3(4, 32, 5), 256, 0, stream>>>(qkvb, Wb, qcat, kcat, qfkfT, vpb);

    // 4) qf2,kf2 -> cat right halves + vp2T = Wfc.vp^T (768 blocks)
    mega2_kernel<<<dim3(4, 8, 24), 256, 0, stream>>>(featb, qfkfT, Wb + 5 * WE, vpb,
                                                     qcat, kcat, vp2T);

    // 5) attn = tanh(mask(qcat.kcat^T / temp)), K=1024 (256 blocks)
    scores_kernel<<<dim3(4, 8, 8), 256, 0, stream>>>(qcat, kcat, lens, attnf, attnb);

    // 6) out2 = attn @ vp2 (256 blocks)
    av2_kernel<<<dim3(4, 8, 8), 256, 0, stream>>>(attnb, vp2T, out2);

    // 7) LayerNorm(out2 + q)
    ln_kernel<<<4096, 64, 0, stream>>>(out2, q, gamma, beta, outp);
}